// Round 1
// baseline (919.290 us; speedup 1.0000x reference)
//
#include <hip/hip_runtime.h>

// Problem constants (B,C,H,W = 8,64,128,128; K=3)
#define BATCH 8
#define CIN   64
#define OUT_C 64
#define HH    128
#define WW    128
#define HW    16384      // 128*128
#define K2    9
#define CK    576        // CIN*K2

// ---------------- ws layout (floats) ----------------
// dwT    [576][64]            offset 0        (36864 floats)
// wfT    [576][27]            offset 36864    (15552 floats)
// offmask[B][27][H][W]        offset 52416    (3538944 floats)
// total 3,591,360 floats = 14.4 MB

// Transpose weights into compute-friendly layouts.
__global__ void prep_kernel(const float* __restrict__ ow, const float* __restrict__ mw,
                            const float* __restrict__ dw,
                            float* __restrict__ dwT, float* __restrict__ wfT) {
    int t = blockIdx.x * 256 + threadIdx.x;
    if (t < CK * OUT_C) {               // dwT[s][o] = dw[o][s],  s = c*9+k
        int o = t & 63, s = t >> 6;
        dwT[t] = dw[o * CK + s];
    }
    if (t < CK * 27) {                  // wfT[ct][j], ct = c*9+t9
        int j = t % 27, ct = t / 27;
        wfT[t] = (j < 18) ? ow[j * CK + ct] : mw[(j - 18) * CK + ct];
    }
}

// 3x3 SAME conv producing 18 offset planes (raw) + 9 mask planes (sigmoid).
// Block: one (b, row-pair): 2 rows x 128 cols = 256 threads, one pixel each.
__global__ __launch_bounds__(256) void conv_offmask(
        const float* __restrict__ x, const float* __restrict__ wfT,
        const float* __restrict__ ob, const float* __restrict__ mb,
        float* __restrict__ offmask) {
    // tile: 16 channels x 4 rows x 130 cols (zero-padded halo) = 33,280 B
    __shared__ float tile[16 * 4 * 130];
    int b  = blockIdx.x >> 6;
    int rp = blockIdx.x & 63;
    int h0 = rp * 2;
    int t  = threadIdx.x;
    int col = t & 127, r = t >> 7;   // r in {0,1}
    int h = h0 + r;

    float acc[27];
#pragma unroll
    for (int j = 0; j < 27; j++) acc[j] = 0.f;

    for (int c0 = 0; c0 < CIN; c0 += 16) {
        __syncthreads();   // previous tile fully consumed
        for (int e = t; e < 16 * 4 * 130; e += 256) {
            int cc  = e / 520;
            int rem = e - cc * 520;
            int rr  = rem / 130;
            int cl  = rem - rr * 130 - 1;     // -1..128
            int gr  = h0 - 1 + rr;            // -1..128
            float v = 0.f;
            if ((unsigned)gr < 128u && (unsigned)cl < 128u)
                v = x[(((b * CIN + c0 + cc) << 7) + gr) * 128 + cl];
            tile[e] = v;
        }
        __syncthreads();
#pragma unroll 1
        for (int cc = 0; cc < 16; cc++) {
            float xv[9];
#pragma unroll
            for (int dr = 0; dr < 3; dr++)
#pragma unroll
                for (int dc = 0; dc < 3; dc++)
                    xv[dr * 3 + dc] = tile[cc * 520 + (r + dr) * 130 + (col + dc)];
            const float* __restrict__ wr = wfT + (c0 + cc) * 9 * 27;  // uniform -> s_load
#pragma unroll
            for (int t9 = 0; t9 < 9; t9++) {
                float xb = xv[t9];
#pragma unroll
                for (int j = 0; j < 27; j++)
                    acc[j] = fmaf(wr[t9 * 27 + j], xb, acc[j]);
            }
        }
    }

    int base = (b * 27) * HW + (h << 7) + col;
#pragma unroll
    for (int j = 0; j < 27; j++) {
        float v = acc[j];
        if (j < 18) v += ob[j];
        else {
            v += mb[j - 18];
            v = 1.f / (1.f + __expf(-v));   // sigmoid
        }
        offmask[base + j * HW] = v;
    }
}

// Deformable conv: block = 32 consecutive pixels of one row.
// Phase 0: bilinear params per (px,k). Phase 1: gather samp[32][576] into LDS.
// Phase 2: out[o] = sum_s samp[s]*dwT[s][o] (+db), 8 o's per thread.
#define SSTRIDE 580   // 2320 B row: 16B-aligned float4, non-pow2 bank stride
__global__ __launch_bounds__(256) void deform_kernel(
        const float* __restrict__ x, const float* __restrict__ offmask,
        const float* __restrict__ dwT, const float* __restrict__ dbv,
        float* __restrict__ out) {
    __shared__ __align__(16) float samp[32 * SSTRIDE];   // 74,240 B
    __shared__ float wgt[4 * 288];                       //  4,608 B
    __shared__ int   pidx[288];                          //  1,152 B

    int t   = threadIdx.x;
    int blk = blockIdx.x;
    int b   = blk >> 9;
    int rem = blk & 511;
    int h   = rem >> 2;
    int wb  = (rem & 3) << 5;

    // ---- Phase 0: bilinear weights (mask-premult, validity-zeroed) + packed idx
    for (int m = t; m < 288; m += 256) {
        int p = m / 9, k = m - p * 9;
        int wp = wb + p;
        int obase = (b * 27) * HW + (h << 7) + wp;
        float dy = offmask[obase + (2 * k) * HW];
        float dx = offmask[obase + (2 * k + 1) * HW];
        float mk = offmask[obase + (18 + k) * HW];
        float py = (float)h  + (float)(k / 3 - 1) + dy;
        float px = (float)wp + (float)(k % 3 - 1) + dx;
        float fy = floorf(py), fx = floorf(px);
        float ly = py - fy, lx = px - fx;
        int y0 = (int)fy, x0 = (int)fx;
        bool y0v = (unsigned)y0 < 128u, y1v = (unsigned)(y0 + 1) < 128u;
        bool x0v = (unsigned)x0 < 128u, x1v = (unsigned)(x0 + 1) < 128u;
        float w00 = (y0v && x0v) ? (1.f - ly) * (1.f - lx) * mk : 0.f;
        float w01 = (y0v && x1v) ? (1.f - ly) * lx * mk : 0.f;
        float w10 = (y1v && x0v) ? ly * (1.f - lx) * mk : 0.f;
        float w11 = (y1v && x1v) ? ly * lx * mk : 0.f;
        int y0c = min(max(y0, 0), 127), x0c = min(max(x0, 0), 127);
        int dxb = (x0 >= 0 && x0 < 127) ? 1 : 0;
        int dyb = (y0 >= 0 && y0 < 127) ? 1 : 0;
        wgt[m]           = w00;
        wgt[288 + m]     = w01;
        wgt[576 + m]     = w10;
        wgt[864 + m]     = w11;
        pidx[m] = (y0c * 128 + x0c) | (dxb << 14) | (dyb << 15);
    }
    __syncthreads();

    // ---- Phase 1: gather. lanes: p = t&31 (coalesced-ish in w), j = t>>5
    {
        int p = t & 31, j = t >> 5;
        const float* __restrict__ xb = x + (b * CIN) * HW;
        for (int i = 0; i < 72; i++) {
            int s = j + (i << 3);          // covers 0..575
            int c = s / 9, k = s - c * 9;
            int m = p * 9 + k;
            float w00 = wgt[m], w01 = wgt[288 + m], w10 = wgt[576 + m], w11 = wgt[864 + m];
            int pk  = pidx[m];
            int i00 = pk & 0x3FFF;
            int dxb = (pk >> 14) & 1;
            int dyo = ((pk >> 15) & 1) << 7;
            const float* __restrict__ xc = xb + c * HW;
            float v00 = xc[i00];
            float v01 = xc[i00 + dxb];
            float v10 = xc[i00 + dyo];
            float v11 = xc[i00 + dyo + dxb];
            samp[p * SSTRIDE + s] = w00 * v00 + w01 * v01 + w10 * v10 + w11 * v11;
        }
    }
    __syncthreads();

    // ---- Phase 2: matvec. thread = (pixel p2, 8 outputs og*8..+7)
    {
        int p2 = t & 31, og = t >> 5;
        float acc[8];
#pragma unroll
        for (int oo = 0; oo < 8; oo++) acc[oo] = dbv[og * 8 + oo];
        for (int s4 = 0; s4 < 144; s4++) {
            float4 sv = *(const float4*)&samp[p2 * SSTRIDE + (s4 << 2)];
#pragma unroll
            for (int q = 0; q < 4; q++) {
                float sq = (q == 0) ? sv.x : (q == 1) ? sv.y : (q == 2) ? sv.z : sv.w;
                const float* wrow = dwT + ((s4 << 2) + q) * 64 + og * 8;
                float4 wlo = *(const float4*)&wrow[0];
                float4 whi = *(const float4*)&wrow[4];
                acc[0] = fmaf(sq, wlo.x, acc[0]);
                acc[1] = fmaf(sq, wlo.y, acc[1]);
                acc[2] = fmaf(sq, wlo.z, acc[2]);
                acc[3] = fmaf(sq, wlo.w, acc[3]);
                acc[4] = fmaf(sq, whi.x, acc[4]);
                acc[5] = fmaf(sq, whi.y, acc[5]);
                acc[6] = fmaf(sq, whi.z, acc[6]);
                acc[7] = fmaf(sq, whi.w, acc[7]);
            }
        }
        int pixoff = (h << 7) + wb + p2;
#pragma unroll
        for (int oo = 0; oo < 8; oo++)
            out[(b * OUT_C + og * 8 + oo) * HW + pixoff] = acc[oo];
    }
}

extern "C" void kernel_launch(void* const* d_in, const int* in_sizes, int n_in,
                              void* d_out, int out_size, void* d_ws, size_t ws_size,
                              hipStream_t stream) {
    const float* x   = (const float*)d_in[0];
    const float* ow  = (const float*)d_in[1];
    const float* ob  = (const float*)d_in[2];
    const float* mw  = (const float*)d_in[3];
    const float* mb  = (const float*)d_in[4];
    const float* dw  = (const float*)d_in[5];
    const float* dbv = (const float*)d_in[6];
    float* out = (float*)d_out;
    float* ws  = (float*)d_ws;

    float* dwT     = ws;              // 36864 floats
    float* wfT     = ws + 36864;      // 15552 floats
    float* offmask = ws + 52416;      // 3538944 floats

    prep_kernel<<<144, 256, 0, stream>>>(ow, mw, dw, dwT, wfT);
    conv_offmask<<<BATCH * 64, 256, 0, stream>>>(x, wfT, ob, mb, offmask);
    deform_kernel<<<BATCH * 512, 256, 0, stream>>>(x, offmask, dwT, dbv, out);
}

// Round 2
// 674.728 us; speedup vs baseline: 1.3625x; 1.3625x over previous
//
#include <hip/hip_runtime.h>

// Problem constants (B,C,H,W = 8,64,128,128; K=3)
#define BATCH 8
#define CIN   64
#define OUT_C 64
#define HH    128
#define WW    128
#define HW    16384      // 128*128
#define K2    9
#define CK    576        // CIN*K2

// ---------------- ws layout (floats) ----------------
// dwT    [576][64]            offset 0        (36864 floats)
// wfT    [576][27]            offset 36864    (15552 floats)
// offmask[B][27][H][W]        offset 52416    (3538944 floats)

// Transpose weights into compute-friendly layouts.
__global__ void prep_kernel(const float* __restrict__ ow, const float* __restrict__ mw,
                            const float* __restrict__ dw,
                            float* __restrict__ dwT, float* __restrict__ wfT) {
    int t = blockIdx.x * 256 + threadIdx.x;
    if (t < CK * OUT_C) {               // dwT[s][o] = dw[o][s],  s = c*9+k
        int o = t & 63, s = t >> 6;
        dwT[t] = dw[o * CK + s];
    }
    if (t < CK * 27) {                  // wfT[ct][j], ct = c*9+t9
        int j = t % 27, ct = t / 27;
        wfT[t] = (j < 18) ? ow[j * CK + ct] : mw[(j - 18) * CK + ct];
    }
}

// 3x3 SAME conv producing 18 offset planes (raw) + 9 mask planes (sigmoid).
// Block: one (b, row-pair): 2 rows x 128 cols = 256 threads, one pixel each.
__global__ __launch_bounds__(256) void conv_offmask(
        const float* __restrict__ x, const float* __restrict__ wfT,
        const float* __restrict__ ob, const float* __restrict__ mb,
        float* __restrict__ offmask) {
    // tile: 16 channels x 4 rows x 130 cols (zero-padded halo) = 33,280 B
    __shared__ float tile[16 * 4 * 130];
    int b  = blockIdx.x >> 6;
    int rp = blockIdx.x & 63;
    int h0 = rp * 2;
    int t  = threadIdx.x;
    int col = t & 127, r = t >> 7;   // r in {0,1}
    int h = h0 + r;

    float acc[27];
#pragma unroll
    for (int j = 0; j < 27; j++) acc[j] = 0.f;

    for (int c0 = 0; c0 < CIN; c0 += 16) {
        __syncthreads();   // previous tile fully consumed
        for (int e = t; e < 16 * 4 * 130; e += 256) {
            int cc  = e / 520;
            int rem = e - cc * 520;
            int rr  = rem / 130;
            int cl  = rem - rr * 130 - 1;     // -1..128
            int gr  = h0 - 1 + rr;            // -1..128
            float v = 0.f;
            if ((unsigned)gr < 128u && (unsigned)cl < 128u)
                v = x[(((b * CIN + c0 + cc) << 7) + gr) * 128 + cl];
            tile[e] = v;
        }
        __syncthreads();
#pragma unroll 1
        for (int cc = 0; cc < 16; cc++) {
            float xv[9];
#pragma unroll
            for (int dr = 0; dr < 3; dr++)
#pragma unroll
                for (int dc = 0; dc < 3; dc++)
                    xv[dr * 3 + dc] = tile[cc * 520 + (r + dr) * 130 + (col + dc)];
            const float* __restrict__ wr = wfT + (c0 + cc) * 9 * 27;  // uniform -> s_load
#pragma unroll
            for (int t9 = 0; t9 < 9; t9++) {
                float xb = xv[t9];
#pragma unroll
                for (int j = 0; j < 27; j++)
                    acc[j] = fmaf(wr[t9 * 27 + j], xb, acc[j]);
            }
        }
    }

    int base = (b * 27) * HW + (h << 7) + col;
#pragma unroll
    for (int j = 0; j < 27; j++) {
        float v = acc[j];
        if (j < 18) v += ob[j];
        else {
            v += mb[j - 18];
            v = 1.f / (1.f + __expf(-v));   // sigmoid
        }
        offmask[base + j * HW] = v;
    }
}

// Deformable conv, LDS-free. Thread = (pixel, half of the 64 outputs).
// 32 fp32 accumulators in VGPRs; bilinear params precomputed per thread;
// weights read via wave-uniform pointer (readfirstlane) -> s_load -> SGPR FMA.
__global__ __launch_bounds__(256, 4) void deform_kernel(
        const float* __restrict__ x, const float* __restrict__ offmask,
        const float* __restrict__ dwT, const float* __restrict__ dbv,
        float* __restrict__ out) {
    int t = threadIdx.x;
    int lane_px = t & 127;                                   // pixel within row
    int half = __builtin_amdgcn_readfirstlane(t >> 7);       // wave-uniform!
    int blk = blockIdx.x;
    int b = blk >> 7;          // batch
    int h = blk & 127;         // row
    int pix = (h << 7) + lane_px;

    // ---- bilinear params per k: 4 weights (validity-zeroed, mask premult)
    //      + packed byte offsets: base | dxb<<17 | dyb<<18
    float w00[9], w01[9], w10[9], w11[9];
    int pk[9];
    const float* __restrict__ om = offmask + (b * 27) * HW + pix;
    float hy = (float)h, wxf = (float)lane_px;
#pragma unroll
    for (int k = 0; k < 9; k++) {
        float dy = om[(2 * k) * HW];
        float dx = om[(2 * k + 1) * HW];
        float mk = om[(18 + k) * HW];
        float py  = hy  + (float)(k / 3 - 1) + dy;
        float pxx = wxf + (float)(k % 3 - 1) + dx;
        float fy = floorf(py), fx = floorf(pxx);
        float ly = py - fy, lx = pxx - fx;
        int y0 = (int)fy, x0 = (int)fx;
        bool y0v = (unsigned)y0 < 128u, y1v = (unsigned)(y0 + 1) < 128u;
        bool x0v = (unsigned)x0 < 128u, x1v = (unsigned)(x0 + 1) < 128u;
        w00[k] = (y0v && x0v) ? (1.f - ly) * (1.f - lx) * mk : 0.f;
        w01[k] = (y0v && x1v) ? (1.f - ly) * lx * mk : 0.f;
        w10[k] = (y1v && x0v) ? ly * (1.f - lx) * mk : 0.f;
        w11[k] = (y1v && x1v) ? ly * lx * mk : 0.f;
        int y0c = min(max(y0, 0), 127), x0c = min(max(x0, 0), 127);
        int base = ((y0c << 7) + x0c) << 2;                   // byte offset
        int dxb = (x0 >= 0 && x0 < 127) ? 1 : 0;
        int dyb = (y0 >= 0 && y0 < 127) ? 1 : 0;
        pk[k] = base | (dxb << 17) | (dyb << 18);
    }

    // ---- accumulators
    float acc[32];
    const float* __restrict__ dbh = dbv + half * 32;          // uniform
#pragma unroll
    for (int oo = 0; oo < 32; oo++) acc[oo] = dbh[oo];

    const char* __restrict__ xb = (const char*)(x + (b * CIN) * HW);
    const float* __restrict__ wbase = dwT + half * 32;        // uniform

#pragma unroll 1
    for (int c = 0; c < CIN; c++) {
        const char* __restrict__ xc = xb + c * (HW * 4);
#pragma unroll
        for (int k = 0; k < 9; k++) {
            int p = pk[k];
            int o00 = p & 0x1FFFF;
            int ddx = (p >> 15) & 4;      // 0 or 4 bytes
            int ddy = (p >> 9) & 0x200;   // 0 or 512 bytes
            float v00 = *(const float*)(xc + o00);
            float v01 = *(const float*)(xc + (o00 + ddx));
            float v10 = *(const float*)(xc + (o00 + ddy));
            float v11 = *(const float*)(xc + (o00 + ddy + ddx));
            float s = w00[k] * v00;
            s = fmaf(w01[k], v01, s);
            s = fmaf(w10[k], v10, s);
            s = fmaf(w11[k], v11, s);
            const float* __restrict__ wr = wbase + (c * 9 + k) * 64;  // uniform -> s_load
#pragma unroll
            for (int oo = 0; oo < 32; oo++)
                acc[oo] = fmaf(s, wr[oo], acc[oo]);
        }
    }

    int obase = (b * OUT_C + half * 32) * HW + pix;
#pragma unroll
    for (int oo = 0; oo < 32; oo++)
        out[obase + oo * HW] = acc[oo];
}

extern "C" void kernel_launch(void* const* d_in, const int* in_sizes, int n_in,
                              void* d_out, int out_size, void* d_ws, size_t ws_size,
                              hipStream_t stream) {
    const float* x   = (const float*)d_in[0];
    const float* ow  = (const float*)d_in[1];
    const float* ob  = (const float*)d_in[2];
    const float* mw  = (const float*)d_in[3];
    const float* mb  = (const float*)d_in[4];
    const float* dw  = (const float*)d_in[5];
    const float* dbv = (const float*)d_in[6];
    float* out = (float*)d_out;
    float* ws  = (float*)d_ws;

    float* dwT     = ws;              // 36864 floats
    float* wfT     = ws + 36864;      // 15552 floats
    float* offmask = ws + 52416;      // 3538944 floats

    prep_kernel<<<144, 256, 0, stream>>>(ow, mw, dw, dwT, wfT);
    conv_offmask<<<BATCH * 64, 256, 0, stream>>>(x, wfT, ob, mb, offmask);
    deform_kernel<<<BATCH * 128, 256, 0, stream>>>(x, offmask, dwT, dbv, out);
}

// Round 3
// 421.479 us; speedup vs baseline: 2.1811x; 1.6009x over previous
//
#include <hip/hip_runtime.h>

// Problem constants (B,C,H,W = 8,64,128,128; K=3)
#define BATCH 8
#define CIN   64
#define OUT_C 64
#define HW    16384      // 128*128
#define CK    576        // CIN*K2

typedef __attribute__((ext_vector_type(8))) short bf16x8;
typedef __attribute__((ext_vector_type(4))) float f32x4;

__device__ inline unsigned short f2bf(float f) {
    unsigned int u = __builtin_bit_cast(unsigned int, f);
    u += 0x7FFFu + ((u >> 16) & 1u);          // round-to-nearest-even
    return (unsigned short)(u >> 16);
}

// ---------------- ws layout ----------------
// wpack  [18][4][64][8] bf16 (ushort)   at ws[0]        (36864 ush = 18432 fl)
// wfT    [576][27] fp32                 at ws+36864
// offmask[B][27][H][W] fp32             at ws+52416

// K-ordering for the deform GEMM: s = k*64 + c  (k-major).
// wpack fragment order: A[m=o=otile*16+(lane&15)][k = gks*32+(lane>>4)*8+j]
__global__ void prep_kernel(const float* __restrict__ ow, const float* __restrict__ mw,
                            const float* __restrict__ dw,
                            unsigned short* __restrict__ wpack, float* __restrict__ wfT) {
    int t = blockIdx.x * 256 + threadIdx.x;
    if (t < 18 * 4 * 64 * 8) {
        int j = t & 7, lane = (t >> 3) & 63, otile = (t >> 9) & 3, gks = t >> 11;
        int o = otile * 16 + (lane & 15);
        int s = gks * 32 + ((lane >> 4) & 3) * 8 + j;
        int c = s & 63, kk = s >> 6;
        wpack[t] = f2bf(dw[o * CK + c * 9 + kk]);
    }
    if (t < CK * 27) {
        int j = t % 27, ct = t / 27;
        wfT[t] = (j < 18) ? ow[j * CK + ct] : mw[(j - 18) * CK + ct];
    }
}

// 3x3 SAME conv producing 18 offset planes (raw) + 9 mask planes (sigmoid).
__global__ __launch_bounds__(256) void conv_offmask(
        const float* __restrict__ x, const float* __restrict__ wfT,
        const float* __restrict__ ob, const float* __restrict__ mb,
        float* __restrict__ offmask) {
    __shared__ float tile[16 * 4 * 130];
    int b  = blockIdx.x >> 6;
    int rp = blockIdx.x & 63;
    int h0 = rp * 2;
    int t  = threadIdx.x;
    int col = t & 127, r = t >> 7;
    int h = h0 + r;

    float acc[27];
#pragma unroll
    for (int j = 0; j < 27; j++) acc[j] = 0.f;

    for (int c0 = 0; c0 < CIN; c0 += 16) {
        __syncthreads();
        for (int e = t; e < 16 * 4 * 130; e += 256) {
            int cc  = e / 520;
            int rem = e - cc * 520;
            int rr  = rem / 130;
            int cl  = rem - rr * 130 - 1;
            int gr  = h0 - 1 + rr;
            float v = 0.f;
            if ((unsigned)gr < 128u && (unsigned)cl < 128u)
                v = x[(((b * CIN + c0 + cc) << 7) + gr) * 128 + cl];
            tile[e] = v;
        }
        __syncthreads();
#pragma unroll 1
        for (int cc = 0; cc < 16; cc++) {
            float xv[9];
#pragma unroll
            for (int dr = 0; dr < 3; dr++)
#pragma unroll
                for (int dc = 0; dc < 3; dc++)
                    xv[dr * 3 + dc] = tile[cc * 520 + (r + dr) * 130 + (col + dc)];
            const float* __restrict__ wr = wfT + (c0 + cc) * 9 * 27;
#pragma unroll
            for (int t9 = 0; t9 < 9; t9++) {
                float xb = xv[t9];
#pragma unroll
                for (int j = 0; j < 27; j++)
                    acc[j] = fmaf(wr[t9 * 27 + j], xb, acc[j]);
            }
        }
    }

    int base = (b * 27) * HW + (h << 7) + col;
#pragma unroll
    for (int j = 0; j < 27; j++) {
        float v = acc[j];
        if (j < 18) v += ob[j];
        else {
            v += mb[j - 18];
            v = 1.f / (1.f + __expf(-v));
        }
        offmask[base + j * HW] = v;
    }
}

// Deformable conv as MFMA GEMM. Block = 64 px (half row) x 64 outputs.
// Gather samp[64px][K-chunk] bf16 into LDS (K = k*64+c, chunks k0-3 / k4-8),
// then D[o][px] += A(weights,frag-packed) * B(samp).
#define SROW 328   // 320 + 8 pad bf16; 656 B row -> bank-start 4*(px+quad)%32
__global__ __launch_bounds__(256, 3) void deform_kernel(
        const float* __restrict__ x, const float* __restrict__ offmask,
        const unsigned short* __restrict__ wpack, const float* __restrict__ dbv,
        float* __restrict__ out) {
    __shared__ unsigned short samp[64 * SROW];   // 41,984 B
    int t = threadIdx.x;
    int lane = t & 63;
    int w = t >> 6;                 // wave id (wave-uniform)
    int quad = lane >> 4;
    int blk = blockIdx.x;
    int b  = blk >> 8;
    int h  = (blk >> 1) & 127;
    int hf = blk & 1;
    int px0 = hf << 6;
    int gx = px0 + lane;            // image column for this lane's pixel

    // ---- bilinear params per k (R2-verified packed scheme)
    float w00[9], w01[9], w10[9], w11[9];
    int pk[9];
    const float* __restrict__ om = offmask + (b * 27) * HW + (h << 7) + gx;
    float hyf = (float)h, wxf = (float)gx;
#pragma unroll
    for (int k = 0; k < 9; k++) {
        float dy = om[(2 * k) * HW];
        float dx = om[(2 * k + 1) * HW];
        float mk = om[(18 + k) * HW];
        float py  = hyf + (float)(k / 3 - 1) + dy;
        float pxx = wxf + (float)(k % 3 - 1) + dx;
        float fy = floorf(py), fx = floorf(pxx);
        float ly = py - fy, lx = pxx - fx;
        int y0 = (int)fy, x0 = (int)fx;
        bool y0v = (unsigned)y0 < 128u, y1v = (unsigned)(y0 + 1) < 128u;
        bool x0v = (unsigned)x0 < 128u, x1v = (unsigned)(x0 + 1) < 128u;
        w00[k] = (y0v && x0v) ? (1.f - ly) * (1.f - lx) * mk : 0.f;
        w01[k] = (y0v && x1v) ? (1.f - ly) * lx * mk : 0.f;
        w10[k] = (y1v && x0v) ? ly * (1.f - lx) * mk : 0.f;
        w11[k] = (y1v && x1v) ? ly * lx * mk : 0.f;
        int y0c = min(max(y0, 0), 127), x0c = min(max(x0, 0), 127);
        int base = ((y0c << 7) + x0c) << 2;
        int dxb = (x0 >= 0 && x0 < 127) ? 1 : 0;
        int dyb = (y0 >= 0 && y0 < 127) ? 1 : 0;
        pk[k] = base | (dxb << 17) | (dyb << 18);
    }

    // ---- accumulators, bias-initialized.  D row = o = w*16 + quad*4 + reg
    int obase_o = (w << 4) + (quad << 2);
    f32x4 bias;
#pragma unroll
    for (int r = 0; r < 4; r++) bias[r] = dbv[obase_o + r];
    f32x4 acc[4];
#pragma unroll
    for (int pt = 0; pt < 4; pt++) acc[pt] = bias;

    const char* __restrict__ xb = (const char*)(x + b * CIN * HW);
    int kbase = 0;
#pragma unroll
    for (int chunk = 0; chunk < 2; chunk++) {
        int knum = chunk ? 5 : 4;
        // ---- gather: wave w owns channels [w*16, w*16+16), all k of chunk
#pragma unroll 1
        for (int kk = 0; kk < knum; kk++) {
            int k = kbase + kk;
            float W00 = w00[k], W01 = w01[k], W10 = w10[k], W11 = w11[k];
            int p = pk[k];
            int o00 = p & 0x1FFFF;
            int ddx = (p >> 15) & 4;
            int ddy = (p >> 9) & 0x200;
            int o01 = o00 + ddx, o10 = o00 + ddy, o11 = o10 + ddx;
#pragma unroll
            for (int cg = 0; cg < 2; cg++) {
                bf16x8 pv;
#pragma unroll
                for (int ci = 0; ci < 8; ci++) {
                    const char* __restrict__ xc =
                        xb + (((w << 4) + (cg << 3) + ci) * (HW * 4));
                    float v00 = *(const float*)(xc + o00);
                    float v01 = *(const float*)(xc + o01);
                    float v10 = *(const float*)(xc + o10);
                    float v11 = *(const float*)(xc + o11);
                    float s = W00 * v00;
                    s = fmaf(W01, v01, s);
                    s = fmaf(W10, v10, s);
                    s = fmaf(W11, v11, s);
                    pv[ci] = (short)f2bf(s);
                }
                *(bf16x8*)&samp[lane * SROW + kk * 64 + (w << 4) + (cg << 3)] = pv;
            }
        }
        __syncthreads();
        // ---- MFMA over this chunk's ksteps
        int nks = chunk ? 10 : 8;
        const unsigned short* __restrict__ wp =
            wpack + (((chunk * 8) * 4 + w) * 64 + lane) * 8;
#pragma unroll 1
        for (int ks = 0; ks < nks; ks++) {
            bf16x8 af = *(const bf16x8*)(wp + ks * (4 * 64 * 8));
#pragma unroll
            for (int pt = 0; pt < 4; pt++) {
                bf16x8 bfr = *(const bf16x8*)
                    &samp[(pt * 16 + (lane & 15)) * SROW + ks * 32 + quad * 8];
                acc[pt] = __builtin_amdgcn_mfma_f32_16x16x32_bf16(af, bfr, acc[pt], 0, 0, 0);
            }
        }
        __syncthreads();
        kbase += knum;
    }

    // ---- epilogue: D[m=o][n=px], col=lane&15, row=quad*4+reg
    int opix = (h << 7) + px0 + (lane & 15);
#pragma unroll
    for (int pt = 0; pt < 4; pt++) {
#pragma unroll
        for (int r = 0; r < 4; r++) {
            out[(b * OUT_C + obase_o + r) * HW + opix + pt * 16] = acc[pt][r];
        }
    }
}

extern "C" void kernel_launch(void* const* d_in, const int* in_sizes, int n_in,
                              void* d_out, int out_size, void* d_ws, size_t ws_size,
                              hipStream_t stream) {
    const float* x   = (const float*)d_in[0];
    const float* ow  = (const float*)d_in[1];
    const float* ob  = (const float*)d_in[2];
    const float* mw  = (const float*)d_in[3];
    const float* mb  = (const float*)d_in[4];
    const float* dw  = (const float*)d_in[5];
    const float* dbv = (const float*)d_in[6];
    float* out = (float*)d_out;
    float* ws  = (float*)d_ws;

    unsigned short* wpack = (unsigned short*)ws;   // 36864 ush
    float* wfT     = ws + 36864;                   // 15552 floats
    float* offmask = ws + 52416;                   // 3538944 floats

    prep_kernel<<<144, 256, 0, stream>>>(ow, mw, dw, wpack, wfT);
    conv_offmask<<<BATCH * 64, 256, 0, stream>>>(x, wfT, ob, mb, offmask);
    deform_kernel<<<BATCH * 128 * 2, 256, 0, stream>>>(x, offmask, wpack, dbv, out);
}

// Round 4
// 404.211 us; speedup vs baseline: 2.2743x; 1.0427x over previous
//
#include <hip/hip_runtime.h>

// Problem constants (B,C,H,W = 8,64,128,128; K=3)
#define BATCH 8
#define CIN   64
#define OUT_C 64
#define HW    16384      // 128*128
#define CK    576        // CIN*K2

typedef __attribute__((ext_vector_type(8))) short bf16x8;
typedef __attribute__((ext_vector_type(4))) float f32x4;

__device__ inline unsigned short f2bf(float f) {
    unsigned int u = __builtin_bit_cast(unsigned int, f);
    u += 0x7FFFu + ((u >> 16) & 1u);          // round-to-nearest-even
    return (unsigned short)(u >> 16);
}

// ---------------- ws layout ----------------
// wpack  [18][4][64][8] bf16 (ushort)   at ws[0]        (36864 ush = 18432 fl)
// wfT    [576][27] fp32                 at ws+36864
// offmask[B][27][H][W] fp32             at ws+52416

// K-ordering for the deform GEMM: s = k*64 + c  (k-major).
// wpack fragment order: A[m=o=otile*16+(lane&15)][k = gks*32+(lane>>4)*8+j]
__global__ void prep_kernel(const float* __restrict__ ow, const float* __restrict__ mw,
                            const float* __restrict__ dw,
                            unsigned short* __restrict__ wpack, float* __restrict__ wfT) {
    int t = blockIdx.x * 256 + threadIdx.x;
    if (t < 18 * 4 * 64 * 8) {
        int j = t & 7, lane = (t >> 3) & 63, otile = (t >> 9) & 3, gks = t >> 11;
        int o = otile * 16 + (lane & 15);
        int s = gks * 32 + ((lane >> 4) & 3) * 8 + j;
        int c = s & 63, kk = s >> 6;
        wpack[t] = f2bf(dw[o * CK + c * 9 + kk]);
    }
    if (t < CK * 27) {
        int j = t % 27, ct = t / 27;
        wfT[t] = (j < 18) ? ow[j * CK + ct] : mw[(j - 18) * CK + ct];
    }
}

// 3x3 SAME conv producing 18 offset planes (raw) + 9 mask planes (sigmoid).
// XCD-swizzled: b = blk&7 so each XCD works on one batch (x slice fits L2).
__global__ __launch_bounds__(256) void conv_offmask(
        const float* __restrict__ x, const float* __restrict__ wfT,
        const float* __restrict__ ob, const float* __restrict__ mb,
        float* __restrict__ offmask) {
    __shared__ float tile[16 * 4 * 130];
    int b  = blockIdx.x & 7;
    int rp = blockIdx.x >> 3;
    int h0 = rp * 2;
    int t  = threadIdx.x;
    int col = t & 127, r = t >> 7;
    int h = h0 + r;

    float acc[27];
#pragma unroll
    for (int j = 0; j < 27; j++) acc[j] = 0.f;

    for (int c0 = 0; c0 < CIN; c0 += 16) {
        __syncthreads();
        for (int e = t; e < 16 * 4 * 130; e += 256) {
            int cc  = e / 520;
            int rem = e - cc * 520;
            int rr  = rem / 130;
            int cl  = rem - rr * 130 - 1;
            int gr  = h0 - 1 + rr;
            float v = 0.f;
            if ((unsigned)gr < 128u && (unsigned)cl < 128u)
                v = x[(((b * CIN + c0 + cc) << 7) + gr) * 128 + cl];
            tile[e] = v;
        }
        __syncthreads();
#pragma unroll 1
        for (int cc = 0; cc < 16; cc++) {
            float xv[9];
#pragma unroll
            for (int dr = 0; dr < 3; dr++)
#pragma unroll
                for (int dc = 0; dc < 3; dc++)
                    xv[dr * 3 + dc] = tile[cc * 520 + (r + dr) * 130 + (col + dc)];
            const float* __restrict__ wr = wfT + (c0 + cc) * 9 * 27;
#pragma unroll
            for (int t9 = 0; t9 < 9; t9++) {
                float xb = xv[t9];
#pragma unroll
                for (int j = 0; j < 27; j++)
                    acc[j] = fmaf(wr[t9 * 27 + j], xb, acc[j]);
            }
        }
    }

    int base = (b * 27) * HW + (h << 7) + col;
#pragma unroll
    for (int j = 0; j < 27; j++) {
        float v = acc[j];
        if (j < 18) v += ob[j];
        else {
            v += mb[j - 18];
            v = 1.f / (1.f + __expf(-v));
        }
        offmask[base + j * HW] = v;
    }
}

// Deformable conv as MFMA GEMM. Block = 64 px (half row) x 64 outputs.
// XCD-swizzled (b = blk&7); gather is channel-outer / k-inner for L1 reuse.
#define SROW 328   // 320 + 8 pad bf16; 656 B row
__global__ __launch_bounds__(256, 3) void deform_kernel(
        const float* __restrict__ x, const float* __restrict__ offmask,
        const unsigned short* __restrict__ wpack, const float* __restrict__ dbv,
        float* __restrict__ out) {
    __shared__ unsigned short samp[64 * SROW];   // 41,984 B
    int t = threadIdx.x;
    int lane = t & 63;
    int w = t >> 6;                 // wave id (wave-uniform)
    int quad = lane >> 4;
    int blk = blockIdx.x;
    int b  = blk & 7;               // XCD affinity: one batch per XCD
    int r2 = blk >> 3;
    int h  = r2 >> 1;
    int hf = r2 & 1;
    int px0 = hf << 6;
    int gx = px0 + lane;            // image column for this lane's pixel

    // ---- bilinear params per k (R2-verified packed scheme)
    float w00[9], w01[9], w10[9], w11[9];
    int pk[9];
    const float* __restrict__ om = offmask + (b * 27) * HW + (h << 7) + gx;
    float hyf = (float)h, wxf = (float)gx;
#pragma unroll
    for (int k = 0; k < 9; k++) {
        float dy = om[(2 * k) * HW];
        float dx = om[(2 * k + 1) * HW];
        float mk = om[(18 + k) * HW];
        float py  = hyf + (float)(k / 3 - 1) + dy;
        float pxx = wxf + (float)(k % 3 - 1) + dx;
        float fy = floorf(py), fx = floorf(pxx);
        float ly = py - fy, lx = pxx - fx;
        int y0 = (int)fy, x0 = (int)fx;
        bool y0v = (unsigned)y0 < 128u, y1v = (unsigned)(y0 + 1) < 128u;
        bool x0v = (unsigned)x0 < 128u, x1v = (unsigned)(x0 + 1) < 128u;
        w00[k] = (y0v && x0v) ? (1.f - ly) * (1.f - lx) * mk : 0.f;
        w01[k] = (y0v && x1v) ? (1.f - ly) * lx * mk : 0.f;
        w10[k] = (y1v && x0v) ? ly * (1.f - lx) * mk : 0.f;
        w11[k] = (y1v && x1v) ? ly * lx * mk : 0.f;
        int y0c = min(max(y0, 0), 127), x0c = min(max(x0, 0), 127);
        int base = ((y0c << 7) + x0c) << 2;
        int dxb = (x0 >= 0 && x0 < 127) ? 1 : 0;
        int dyb = (y0 >= 0 && y0 < 127) ? 1 : 0;
        pk[k] = base | (dxb << 17) | (dyb << 18);
    }

    // ---- accumulators, bias-initialized.  D row = o = w*16 + quad*4 + reg
    int obase_o = (w << 4) + (quad << 2);
    f32x4 bias;
#pragma unroll
    for (int r = 0; r < 4; r++) bias[r] = dbv[obase_o + r];
    f32x4 acc[4];
#pragma unroll
    for (int pt = 0; pt < 4; pt++) acc[pt] = bias;

    const char* __restrict__ xb = (const char*)(x + b * CIN * HW);
    int kbase = 0;
#pragma unroll
    for (int chunk = 0; chunk < 2; chunk++) {
        const int knum = chunk ? 5 : 4;
        // hoist this chunk's corner offsets out of the channel loop
        int o00c[5], o01c[5], o10c[5], o11c[5];
#pragma unroll
        for (int kk = 0; kk < knum; kk++) {
            int p = pk[kbase + kk];
            int o00 = p & 0x1FFFF;
            int ddx = (p >> 15) & 4;
            int ddy = (p >> 9) & 0x200;
            o00c[kk] = o00; o01c[kk] = o00 + ddx;
            o10c[kk] = o00 + ddy; o11c[kk] = o00 + ddy + ddx;
        }
        // ---- gather: wave w owns channels [w*16, w*16+16)
        //      channel OUTER, k INNER -> the 9 k's reuse the same ~3 rows in L1
#pragma unroll 1
        for (int cg = 0; cg < 2; cg++) {
            bf16x8 pv[5];
#pragma unroll
            for (int ci = 0; ci < 8; ci++) {
                const char* __restrict__ xc =
                    xb + (((w << 4) + (cg << 3) + ci) * (HW * 4));
#pragma unroll
                for (int kk = 0; kk < knum; kk++) {
                    int k = kbase + kk;
                    float v00 = *(const float*)(xc + o00c[kk]);
                    float v01 = *(const float*)(xc + o01c[kk]);
                    float v10 = *(const float*)(xc + o10c[kk]);
                    float v11 = *(const float*)(xc + o11c[kk]);
                    float s = w00[k] * v00;
                    s = fmaf(w01[k], v01, s);
                    s = fmaf(w10[k], v10, s);
                    s = fmaf(w11[k], v11, s);
                    pv[kk][ci] = (short)f2bf(s);
                }
            }
#pragma unroll
            for (int kk = 0; kk < knum; kk++)
                *(bf16x8*)&samp[lane * SROW + kk * 64 + (w << 4) + (cg << 3)] = pv[kk];
        }
        __syncthreads();
        // ---- MFMA over this chunk's ksteps
        int nks = chunk ? 10 : 8;
        const unsigned short* __restrict__ wp =
            wpack + (((chunk * 8) * 4 + w) * 64 + lane) * 8;
#pragma unroll 1
        for (int ks = 0; ks < nks; ks++) {
            bf16x8 af = *(const bf16x8*)(wp + ks * (4 * 64 * 8));
#pragma unroll
            for (int pt = 0; pt < 4; pt++) {
                bf16x8 bfr = *(const bf16x8*)
                    &samp[(pt * 16 + (lane & 15)) * SROW + ks * 32 + quad * 8];
                acc[pt] = __builtin_amdgcn_mfma_f32_16x16x32_bf16(af, bfr, acc[pt], 0, 0, 0);
            }
        }
        __syncthreads();
        kbase += knum;
    }

    // ---- epilogue: D[m=o][n=px], col=lane&15, row=quad*4+reg
    int opix = (h << 7) + px0 + (lane & 15);
#pragma unroll
    for (int pt = 0; pt < 4; pt++) {
#pragma unroll
        for (int r = 0; r < 4; r++) {
            out[(b * OUT_C + obase_o + r) * HW + opix + pt * 16] = acc[pt][r];
        }
    }
}

extern "C" void kernel_launch(void* const* d_in, const int* in_sizes, int n_in,
                              void* d_out, int out_size, void* d_ws, size_t ws_size,
                              hipStream_t stream) {
    const float* x   = (const float*)d_in[0];
    const float* ow  = (const float*)d_in[1];
    const float* ob  = (const float*)d_in[2];
    const float* mw  = (const float*)d_in[3];
    const float* mb  = (const float*)d_in[4];
    const float* dw  = (const float*)d_in[5];
    const float* dbv = (const float*)d_in[6];
    float* out = (float*)d_out;
    float* ws  = (float*)d_ws;

    unsigned short* wpack = (unsigned short*)ws;   // 36864 ush
    float* wfT     = ws + 36864;                   // 15552 floats
    float* offmask = ws + 52416;                   // 3538944 floats

    prep_kernel<<<144, 256, 0, stream>>>(ow, mw, dw, wpack, wfT);
    conv_offmask<<<BATCH * 64, 256, 0, stream>>>(x, wfT, ob, mb, offmask);
    deform_kernel<<<BATCH * 128 * 2, 256, 0, stream>>>(x, offmask, wpack, dbv, out);
}

// Round 5
// 206.831 us; speedup vs baseline: 4.4446x; 1.9543x over previous
//
#include <hip/hip_runtime.h>

// Problem constants (B,C,H,W = 8,64,128,128; K=3)
#define BATCH 8
#define CIN   64
#define HW    16384      // 128*128
#define CK    576        // CIN*K2

typedef __attribute__((ext_vector_type(8))) short bf16x8;
typedef __attribute__((ext_vector_type(4))) float f32x4;

__device__ inline unsigned short f2bf(float f) {
    unsigned int u = __builtin_bit_cast(unsigned int, f);
    u += 0x7FFFu + ((u >> 16) & 1u);          // round-to-nearest-even
    return (unsigned short)(u >> 16);
}
__device__ inline float bf2f(unsigned short u) {
    return __builtin_bit_cast(float, (unsigned)u << 16);
}

// ---------------- ws layout (ushort units) ----------------
// wpack  [18][4][64][8]  deform A-frags      at 0          (36864)
// wcpack [18][2][64][8]  conv A-frags        at 36864      (18432)
// xT     [B][HW][64]     NHWC bf16 input     at 55296      (8388608)
// om2    [B][HW][32]     offsets+mask bf16   at 8443904    (4194304)

// Pack A-operand fragments. Verified layout (R3): A[m=ot*16+(lane&15)]
// [k=gks*32+(lane>>4)*8+j], k-dim ordering s = tap*64 + c.
__global__ void prep_kernel(const float* __restrict__ ow, const float* __restrict__ mw,
                            const float* __restrict__ dw,
                            unsigned short* __restrict__ wpack,
                            unsigned short* __restrict__ wcpack) {
    int t = blockIdx.x * 256 + threadIdx.x;
    if (t < 18 * 4 * 64 * 8) {           // deform weights: dw[o][c][tap]
        int j = t & 7, lane = (t >> 3) & 63, ot = (t >> 9) & 3, gks = t >> 11;
        int o = ot * 16 + (lane & 15);
        int s = gks * 32 + ((lane >> 4) & 3) * 8 + j;
        int c = s & 63, tap = s >> 6;
        wpack[t] = f2bf(dw[o * CK + c * 9 + tap]);
    }
    if (t < 18 * 2 * 64 * 8) {           // conv weights: rows 0-17 ow, 18-26 mw, 27-31 zero
        int j = t & 7, lane = (t >> 3) & 63, ot = (t >> 9) & 1, gks = t >> 10;
        int o = ot * 16 + (lane & 15);
        int s = gks * 32 + ((lane >> 4) & 3) * 8 + j;
        int c = s & 63, tap = s >> 6;
        float v = 0.f;
        if (o < 18)      v = ow[(o * 64 + c) * 9 + tap];
        else if (o < 27) v = mw[((o - 18) * 64 + c) * 9 + tap];
        wcpack[t] = f2bf(v);
    }
}

// NCHW fp32 -> NHWC bf16. Block = (b, row, half-row); wave w handles 16 ch.
__global__ __launch_bounds__(256) void transpose_kernel(
        const float* __restrict__ x, unsigned short* __restrict__ xT) {
    int t = threadIdx.x, blk = blockIdx.x;
    int b = blk & 7, r2 = blk >> 3;
    int h = r2 >> 1, hf = r2 & 1;
    int gx = (hf << 6) + (t & 63);
    int w = t >> 6;
    int pix = (h << 7) + gx;
    const float* __restrict__ xb = x + (b * CIN) * HW + pix;   // coalesced reads
    bf16x8 lo, hi;
#pragma unroll
    for (int i = 0; i < 8; i++) lo[i] = (short)f2bf(xb[(w * 16 + i) * HW]);
#pragma unroll
    for (int i = 0; i < 8; i++) hi[i] = (short)f2bf(xb[(w * 16 + 8 + i) * HW]);
    unsigned short* dst = xT + ((b * HW + pix) << 6) + w * 16;
    *(bf16x8*)dst = lo;
    *(bf16x8*)(dst + 8) = hi;
}

// Offset/mask conv as MFMA GEMM: M=32 (27 used), K=576 (tap*64+c), N=px.
// Block = 64 px (half row), wave = 16-px n-tile. B-frag = direct NHWC load.
__global__ __launch_bounds__(256) void conv_offmask(
        const unsigned short* __restrict__ xT, const unsigned short* __restrict__ wcpack,
        const float* __restrict__ ob, const float* __restrict__ mb,
        unsigned short* __restrict__ om2) {
    int t = threadIdx.x;
    int lane = t & 63, pt = t >> 6, quad = lane >> 4, n = lane & 15;
    int blk = blockIdx.x;
    int b = blk & 7, r2 = blk >> 3;
    int h = r2 >> 1, hf = r2 & 1;
    int gx = (hf << 6) + (pt << 4) + n;

    f32x4 acc0 = {0.f, 0.f, 0.f, 0.f}, acc1 = {0.f, 0.f, 0.f, 0.f};
    const unsigned short* __restrict__ xtb = xT + ((b * HW) << 6);
    const short zs = 0;
    const bf16x8 zv = {zs, zs, zs, zs, zs, zs, zs, zs};

#pragma unroll 1
    for (int tap = 0; tap < 9; tap++) {
        int yy = h + tap / 3 - 1;
        int xx = gx + tap % 3 - 1;
        bool valid = ((unsigned)yy < 128u) && ((unsigned)xx < 128u);
        int yc = min(max(yy, 0), 127), xc = min(max(xx, 0), 127);
        const unsigned short* __restrict__ src = xtb + ((((yc << 7) + xc)) << 6) + quad * 8;
#pragma unroll
        for (int kk = 0; kk < 2; kk++) {
            bf16x8 bfrag = *(const bf16x8*)(src + kk * 32);
            if (!valid) bfrag = zv;
            int gks = tap * 2 + kk;
            bf16x8 a0 = *(const bf16x8*)(wcpack + ((gks * 2 + 0) * 64 + lane) * 8);
            bf16x8 a1 = *(const bf16x8*)(wcpack + ((gks * 2 + 1) * 64 + lane) * 8);
            acc0 = __builtin_amdgcn_mfma_f32_16x16x32_bf16(a0, bfrag, acc0, 0, 0, 0);
            acc1 = __builtin_amdgcn_mfma_f32_16x16x32_bf16(a1, bfrag, acc1, 0, 0, 0);
        }
    }

    // epilogue: D[px=lane&15][o=quad*4+r] (+otile*16). Planes 0-17 raw offsets,
    // 18-26 sigmoid mask, 27-31 zero. Packed row om2[pix][32].
    unsigned short* __restrict__ orow = om2 + ((b * HW + (h << 7) + gx) << 5);
    {
        unsigned short p[4];
#pragma unroll
        for (int r = 0; r < 4; r++) {
            int o = quad * 4 + r;
            p[r] = f2bf(acc0[r] + ob[o]);
        }
        uint2 u;
        u.x = (unsigned)p[0] | ((unsigned)p[1] << 16);
        u.y = (unsigned)p[2] | ((unsigned)p[3] << 16);
        *(uint2*)(orow + quad * 4) = u;
    }
    {
        unsigned short p[4];
#pragma unroll
        for (int r = 0; r < 4; r++) {
            int o = 16 + quad * 4 + r;
            float v = acc1[r];
            if (o < 18) v += ob[o];
            else if (o < 27) { v += mb[o - 18]; v = 1.f / (1.f + __expf(-v)); }
            else v = 0.f;
            p[r] = f2bf(v);
        }
        uint2 u;
        u.x = (unsigned)p[0] | ((unsigned)p[1] << 16);
        u.y = (unsigned)p[2] | ((unsigned)p[3] << 16);
        *(uint2*)(orow + 16 + quad * 4) = u;
    }
}

// Deformable conv, barrier-free MFMA: wave = 16 px x all 64 outputs.
// B-frags built in registers from 4 contiguous NHWC corner loads.
__global__ __launch_bounds__(256) void deform_kernel(
        const unsigned short* __restrict__ xT, const unsigned short* __restrict__ om2,
        const unsigned short* __restrict__ wpack, const float* __restrict__ dbv,
        float* __restrict__ out) {
    __shared__ float wtab[576 * 4];   // per (px,k): 4 bilinear weights (mask premult)
    __shared__ int   ptab[576];       // per (px,k): packed base pix | dxb<<14 | dyb<<15

    int t = threadIdx.x;
    int lane = t & 63, pt = t >> 6, quad = lane >> 4, n = lane & 15;
    int blk = blockIdx.x;
    int b = blk & 7, r2 = blk >> 3;
    int h = r2 >> 1, hf = r2 & 1;
    int px0 = hf << 6;

    // ---- param table (once per block)
    for (int set = t; set < 576; set += 256) {
        int px_l = set / 9, k = set - px_l * 9;
        int gx = px0 + px_l;
        const unsigned short* __restrict__ omr = om2 + ((b * HW + (h << 7) + gx) << 5);
        float dy = bf2f(omr[2 * k]);
        float dx = bf2f(omr[2 * k + 1]);
        float mk = bf2f(omr[18 + k]);
        float py  = (float)h  + (float)(k / 3 - 1) + dy;
        float pxx = (float)gx + (float)(k % 3 - 1) + dx;
        float fy = floorf(py), fx = floorf(pxx);
        float ly = py - fy, lx = pxx - fx;
        int y0 = (int)fy, x0 = (int)fx;
        bool y0v = (unsigned)y0 < 128u, y1v = (unsigned)(y0 + 1) < 128u;
        bool x0v = (unsigned)x0 < 128u, x1v = (unsigned)(x0 + 1) < 128u;
        wtab[set * 4 + 0] = (y0v && x0v) ? (1.f - ly) * (1.f - lx) * mk : 0.f;
        wtab[set * 4 + 1] = (y0v && x1v) ? (1.f - ly) * lx * mk : 0.f;
        wtab[set * 4 + 2] = (y1v && x0v) ? ly * (1.f - lx) * mk : 0.f;
        wtab[set * 4 + 3] = (y1v && x1v) ? ly * lx * mk : 0.f;
        int y0c = min(max(y0, 0), 127), x0c = min(max(x0, 0), 127);
        int dxb = (x0 >= 0 && x0 < 127) ? 1 : 0;
        int dyb = (y0 >= 0 && y0 < 127) ? 1 : 0;
        ptab[set] = ((y0c << 7) + x0c) | (dxb << 14) | (dyb << 15);
    }
    __syncthreads();

    f32x4 acc[4];
#pragma unroll
    for (int ot = 0; ot < 4; ot++) acc[ot] = (f32x4){0.f, 0.f, 0.f, 0.f};

    int px_l = (pt << 4) + n;           // this lane's pixel (within 64-px block)
    int setbase = px_l * 9;
    const unsigned short* __restrict__ xtb = xT + ((b * HW) << 6);

#pragma unroll 1
    for (int tap = 0; tap < 9; tap++) {
        f32x4 wv = *(const f32x4*)&wtab[(setbase + tap) * 4];
        int p = ptab[setbase + tap];
        int base = p & 0x3FFF;
        int dxb  = (p >> 14) & 1;
        int dyo  = ((p >> 15) & 1) << 7;
        const unsigned short* __restrict__ r00 = xtb + (base << 6);
        const unsigned short* __restrict__ r01 = xtb + ((base + dxb) << 6);
        const unsigned short* __restrict__ r10 = xtb + ((base + dyo) << 6);
        const unsigned short* __restrict__ r11 = xtb + ((base + dyo + dxb) << 6);
#pragma unroll
        for (int kk = 0; kk < 2; kk++) {
            int cc = kk * 32 + quad * 8;
            bf16x8 v00 = *(const bf16x8*)(r00 + cc);
            bf16x8 v01 = *(const bf16x8*)(r01 + cc);
            bf16x8 v10 = *(const bf16x8*)(r10 + cc);
            bf16x8 v11 = *(const bf16x8*)(r11 + cc);
            bf16x8 bfrag;
#pragma unroll
            for (int j = 0; j < 8; j++) {
                float s = wv[0] * bf2f((unsigned short)v00[j]);
                s = fmaf(wv[1], bf2f((unsigned short)v01[j]), s);
                s = fmaf(wv[2], bf2f((unsigned short)v10[j]), s);
                s = fmaf(wv[3], bf2f((unsigned short)v11[j]), s);
                bfrag[j] = (short)f2bf(s);
            }
            int gks = tap * 2 + kk;
#pragma unroll
            for (int ot = 0; ot < 4; ot++) {
                bf16x8 af = *(const bf16x8*)(wpack + ((gks * 4 + ot) * 64 + lane) * 8);
                acc[ot] = __builtin_amdgcn_mfma_f32_16x16x32_bf16(af, bfrag, acc[ot], 0, 0, 0);
            }
        }
    }

    // ---- epilogue: D col(lane&15)=px, row(quad*4+r)+ot*16 = o
    int opix = (h << 7) + px0 + (pt << 4) + n;
#pragma unroll
    for (int ot = 0; ot < 4; ot++) {
#pragma unroll
        for (int r = 0; r < 4; r++) {
            int o = ot * 16 + quad * 4 + r;
            out[(b * 64 + o) * HW + opix] = acc[ot][r] + dbv[o];
        }
    }
}

extern "C" void kernel_launch(void* const* d_in, const int* in_sizes, int n_in,
                              void* d_out, int out_size, void* d_ws, size_t ws_size,
                              hipStream_t stream) {
    const float* x   = (const float*)d_in[0];
    const float* ow  = (const float*)d_in[1];
    const float* ob  = (const float*)d_in[2];
    const float* mw  = (const float*)d_in[3];
    const float* mb  = (const float*)d_in[4];
    const float* dw  = (const float*)d_in[5];
    const float* dbv = (const float*)d_in[6];
    float* out = (float*)d_out;

    unsigned short* wpack  = (unsigned short*)d_ws;          // 36864
    unsigned short* wcpack = wpack + 36864;                  // 18432
    unsigned short* xT     = wpack + 55296;                  // 8388608
    unsigned short* om2    = xT + 8388608;                   // 4194304

    prep_kernel<<<144, 256, 0, stream>>>(ow, mw, dw, wpack, wcpack);
    transpose_kernel<<<2048, 256, 0, stream>>>(x, xT);
    conv_offmask<<<2048, 256, 0, stream>>>(xT, wcpack, ob, mb, om2);
    deform_kernel<<<2048, 256, 0, stream>>>(xT, om2, wpack, dbv, out);
}